// Round 1
// baseline (1175.060 us; speedup 1.0000x reference)
//
#include <hip/hip_runtime.h>
#include <hip/hip_bf16.h>
#include <stdint.h>

#define QMAXF 127.0f
#define BM 128
#define BN 128
#define BK 64

typedef __attribute__((ext_vector_type(8))) short bf16x8;
typedef __attribute__((ext_vector_type(4))) float f32x4;

typedef __attribute__((address_space(1))) void gbl_void;
typedef __attribute__((address_space(3))) void lds_void;

__device__ __forceinline__ void gload_lds16(const void* g, void* l) {
    __builtin_amdgcn_global_load_lds((const gbl_void*)g, (lds_void*)l, 16, 0, 0);
}

// Exact RNE float->bf16 (finite inputs only, which holds here).
__device__ __forceinline__ unsigned short f2bf(float f) {
    unsigned int u = __builtin_bit_cast(unsigned int, f);
    unsigned int r = (u + 0x7fffu + ((u >> 16) & 1u)) >> 16;
    return (unsigned short)r;
}

// ---------------------------------------------------------------------------
// Kernel 1: per-token, per-128-col-group quant-dequant of activations.
// One wave per group of 128 floats (2 floats/lane).
// ---------------------------------------------------------------------------
__global__ __launch_bounds__(256) void qd_x_kernel(const float* __restrict__ x,
                                                   unsigned short* __restrict__ xdq,
                                                   long ngroups) {
    long gw = ((long)blockIdx.x * blockDim.x + threadIdx.x) >> 6;
    int lane = threadIdx.x & 63;
    if (gw >= ngroups) return;

    float2 v = *(reinterpret_cast<const float2*>(x) + gw * 64 + lane);
    float a = fmaxf(fabsf(v.x), fabsf(v.y));
#pragma unroll
    for (int off = 32; off; off >>= 1) a = fmaxf(a, __shfl_xor(a, off));

    float scale = a > 0.f ? a / QMAXF : 1.f;
    float qx = fminf(fmaxf(rintf(v.x / scale), -QMAXF), QMAXF);
    float qy = fminf(fmaxf(rintf(v.y / scale), -QMAXF), QMAXF);
    unsigned int packed = (unsigned int)f2bf(qx * scale) | ((unsigned int)f2bf(qy * scale) << 16);
    reinterpret_cast<unsigned int*>(xdq)[gw * 64 + lane] = packed;
}

// ---------------------------------------------------------------------------
// Kernel 2: 128x128 blockwise quant-dequant of weights.
// One 256-thread block per weight block; operands held in registers.
// ---------------------------------------------------------------------------
__global__ __launch_bounds__(256) void qd_w_kernel(const float* __restrict__ w,
                                                   unsigned short* __restrict__ wdq,
                                                   int K) {
    int kb = blockIdx.x, ob = blockIdx.y;
    size_t base = (size_t)ob * 128 * K + (size_t)kb * 128;
    int t = threadIdx.x;

    float4 v[16];
    float a = 0.f;
#pragma unroll
    for (int i = 0; i < 16; i++) {
        int f = i * 256 + t;
        int row = f >> 5, c4 = f & 31;
        v[i] = *reinterpret_cast<const float4*>(w + base + (size_t)row * K + c4 * 4);
        a = fmaxf(a, fmaxf(fmaxf(fabsf(v[i].x), fabsf(v[i].y)),
                           fmaxf(fabsf(v[i].z), fabsf(v[i].w))));
    }
#pragma unroll
    for (int off = 32; off; off >>= 1) a = fmaxf(a, __shfl_xor(a, off));

    __shared__ float red[4];
    if ((t & 63) == 0) red[t >> 6] = a;
    __syncthreads();
    a = fmaxf(fmaxf(red[0], red[1]), fmaxf(red[2], red[3]));

    float scale = a > 0.f ? a / QMAXF : 1.f;
#pragma unroll
    for (int i = 0; i < 16; i++) {
        int f = i * 256 + t;
        int row = f >> 5, c4 = f & 31;
        float q0 = fminf(fmaxf(rintf(v[i].x / scale), -QMAXF), QMAXF);
        float q1 = fminf(fmaxf(rintf(v[i].y / scale), -QMAXF), QMAXF);
        float q2 = fminf(fmaxf(rintf(v[i].z / scale), -QMAXF), QMAXF);
        float q3 = fminf(fmaxf(rintf(v[i].w / scale), -QMAXF), QMAXF);
        uint2 p;
        p.x = (unsigned int)f2bf(q0 * scale) | ((unsigned int)f2bf(q1 * scale) << 16);
        p.y = (unsigned int)f2bf(q2 * scale) | ((unsigned int)f2bf(q3 * scale) << 16);
        *reinterpret_cast<uint2*>(wdq + base + (size_t)row * K + c4 * 4) = p;
    }
}

// ---------------------------------------------------------------------------
// Kernel 3: bf16 GEMM, C[t,o] = sum_k A[t,k]*B[o,k] + bias[o].
// m97 structure: 128x128 tile, BK=64, 4 waves of 4x4 16x16x32 MFMA frags,
// global_load_lds(16B) staging, XCD-swizzled blockIdx.
// ---------------------------------------------------------------------------
__global__ __launch_bounds__(256) void gemm_bt_kernel(
    const unsigned short* __restrict__ A,   // [M,K] bf16 bits
    const unsigned short* __restrict__ Bw,  // [N,K] bf16 bits
    const float* __restrict__ bias,
    float* __restrict__ C,                  // [M,N] f32
    int M, int N, int K) {
    __shared__ alignas(16) unsigned short lA[BM * BK];
    __shared__ alignas(16) unsigned short lB[BN * BK];

    int nTn = N / BN;
    int nwg = gridDim.x;
    int wg = blockIdx.x;
    int swz = (nwg & 7) ? wg : ((wg & 7) * (nwg >> 3) + (wg >> 3));  // XCD swizzle (bijective: nwg%8==0)
    int mt = swz / nTn;
    int nt = swz - mt * nTn;

    int t = threadIdx.x;
    int wid = t >> 6;
    int lane = t & 63;
    int wrow = (wid >> 1) * 64;
    int wcol = (wid & 1) * 64;
    int lr = lane & 15;   // fragment row/col index
    int lq = lane >> 4;   // k-quadrant

    const unsigned short* Abase = A + (size_t)(mt * BM) * K;
    const unsigned short* Bbase = Bw + (size_t)(nt * BN) * K;

    f32x4 acc[4][4];
#pragma unroll
    for (int m = 0; m < 4; m++)
#pragma unroll
        for (int n = 0; n < 4; n++) acc[m][n] = (f32x4){0.f, 0.f, 0.f, 0.f};

    int rowt = t >> 3;  // staging: row within 32-row strip
    int cc = t & 7;     // staging: 16B chunk within row (8 chunks = 128B = 64 bf16)

    for (int k0 = 0; k0 < K; k0 += BK) {
#pragma unroll
        for (int r = 0; r < 4; r++) {
            int row = r * 32 + rowt;
            gload_lds16(Abase + (size_t)row * K + k0 + cc * 8, &lA[(r * 256 + t) * 8]);
        }
#pragma unroll
        for (int r = 0; r < 4; r++) {
            int row = r * 32 + rowt;
            gload_lds16(Bbase + (size_t)row * K + k0 + cc * 8, &lB[(r * 256 + t) * 8]);
        }
        __syncthreads();

#pragma unroll
        for (int kk = 0; kk < 2; kk++) {
            bf16x8 af[4], bfv[4];
#pragma unroll
            for (int m = 0; m < 4; m++)
                af[m] = *reinterpret_cast<const bf16x8*>(
                    &lA[(wrow + m * 16 + lr) * BK + kk * 32 + lq * 8]);
#pragma unroll
            for (int n = 0; n < 4; n++)
                bfv[n] = *reinterpret_cast<const bf16x8*>(
                    &lB[(wcol + n * 16 + lr) * BK + kk * 32 + lq * 8]);
#pragma unroll
            for (int m = 0; m < 4; m++)
#pragma unroll
                for (int n = 0; n < 4; n++)
                    acc[m][n] = __builtin_amdgcn_mfma_f32_16x16x32_bf16(af[m], bfv[n],
                                                                        acc[m][n], 0, 0, 0);
        }
        __syncthreads();
    }

    // Epilogue: bias + store. C/D layout: col = lane&15, row = (lane>>4)*4 + reg.
    float bv[4];
#pragma unroll
    for (int n = 0; n < 4; n++) bv[n] = bias[nt * BN + wcol + n * 16 + lr];

#pragma unroll
    for (int m = 0; m < 4; m++) {
#pragma unroll
        for (int r = 0; r < 4; r++) {
            size_t roff = (size_t)(mt * BM + wrow + m * 16 + lq * 4 + r) * N;
#pragma unroll
            for (int n = 0; n < 4; n++)
                C[roff + nt * BN + wcol + n * 16 + lr] = acc[m][n][r] + bv[n];
        }
    }
}

extern "C" void kernel_launch(void* const* d_in, const int* in_sizes, int n_in,
                              void* d_out, int out_size, void* d_ws, size_t ws_size,
                              hipStream_t stream) {
    const float* x = (const float*)d_in[0];
    const float* w = (const float*)d_in[1];
    const float* bias = (const float*)d_in[2];
    float* y = (float*)d_out;

    int O = in_sizes[2];          // 11008
    int K = in_sizes[1] / O;      // 4096
    int T = in_sizes[0] / K;      // 8192 tokens

    unsigned short* xdq = (unsigned short*)d_ws;
    size_t xbytes = ((size_t)T * K * 2 + 255) & ~(size_t)255;
    unsigned short* wdq = (unsigned short*)((char*)d_ws + xbytes);

    long ngroups = (long)T * (K / 128);
    qd_x_kernel<<<dim3((unsigned)((ngroups + 3) / 4)), dim3(256), 0, stream>>>(x, xdq, ngroups);
    qd_w_kernel<<<dim3(K / 128, O / 128), dim3(256), 0, stream>>>(w, wdq, K);

    int grid = (T / BM) * (O / BN);
    gemm_bt_kernel<<<dim3(grid), dim3(256), 0, stream>>>(xdq, wdq, bias, y, T, O, K);
}

// Round 2
// 866.932 us; speedup vs baseline: 1.3554x; 1.3554x over previous
//
#include <hip/hip_runtime.h>
#include <hip/hip_bf16.h>
#include <stdint.h>

#define QMAXF 127.0f

typedef __attribute__((ext_vector_type(8))) short bf16x8;
typedef __attribute__((ext_vector_type(4))) float f32x4;

typedef __attribute__((address_space(1))) void gbl_void;
typedef __attribute__((address_space(3))) void lds_void;

__device__ __forceinline__ void gload_lds16(const void* g, void* l) {
    __builtin_amdgcn_global_load_lds((const gbl_void*)g, (lds_void*)l, 16, 0, 0);
}

// Exact RNE float->bf16 (finite inputs only, which holds here).
__device__ __forceinline__ unsigned short f2bf(float f) {
    unsigned int u = __builtin_bit_cast(unsigned int, f);
    unsigned int r = (u + 0x7fffu + ((u >> 16) & 1u)) >> 16;
    return (unsigned short)r;
}

// ---------------------------------------------------------------------------
// Kernel 1: per-token, per-128-col-group quant-dequant of activations.
// ---------------------------------------------------------------------------
__global__ __launch_bounds__(256) void qd_x_kernel(const float* __restrict__ x,
                                                   unsigned short* __restrict__ xdq,
                                                   long ngroups) {
    long gw = ((long)blockIdx.x * blockDim.x + threadIdx.x) >> 6;
    int lane = threadIdx.x & 63;
    if (gw >= ngroups) return;

    float2 v = *(reinterpret_cast<const float2*>(x) + gw * 64 + lane);
    float a = fmaxf(fabsf(v.x), fabsf(v.y));
#pragma unroll
    for (int off = 32; off; off >>= 1) a = fmaxf(a, __shfl_xor(a, off));

    float scale = a > 0.f ? a / QMAXF : 1.f;
    float qx = fminf(fmaxf(rintf(v.x / scale), -QMAXF), QMAXF);
    float qy = fminf(fmaxf(rintf(v.y / scale), -QMAXF), QMAXF);
    unsigned int packed = (unsigned int)f2bf(qx * scale) | ((unsigned int)f2bf(qy * scale) << 16);
    reinterpret_cast<unsigned int*>(xdq)[gw * 64 + lane] = packed;
}

// ---------------------------------------------------------------------------
// Kernel 2: 128x128 blockwise quant-dequant of weights.
// ---------------------------------------------------------------------------
__global__ __launch_bounds__(256) void qd_w_kernel(const float* __restrict__ w,
                                                   unsigned short* __restrict__ wdq,
                                                   int K) {
    int kb = blockIdx.x, ob = blockIdx.y;
    size_t base = (size_t)ob * 128 * K + (size_t)kb * 128;
    int t = threadIdx.x;

    float4 v[16];
    float a = 0.f;
#pragma unroll
    for (int i = 0; i < 16; i++) {
        int f = i * 256 + t;
        int row = f >> 5, c4 = f & 31;
        v[i] = *reinterpret_cast<const float4*>(w + base + (size_t)row * K + c4 * 4);
        a = fmaxf(a, fmaxf(fmaxf(fabsf(v[i].x), fabsf(v[i].y)),
                           fmaxf(fabsf(v[i].z), fabsf(v[i].w))));
    }
#pragma unroll
    for (int off = 32; off; off >>= 1) a = fmaxf(a, __shfl_xor(a, off));

    __shared__ float red[4];
    if ((t & 63) == 0) red[t >> 6] = a;
    __syncthreads();
    a = fmaxf(fmaxf(red[0], red[1]), fmaxf(red[2], red[3]));

    float scale = a > 0.f ? a / QMAXF : 1.f;
#pragma unroll
    for (int i = 0; i < 16; i++) {
        int f = i * 256 + t;
        int row = f >> 5, c4 = f & 31;
        float q0 = fminf(fmaxf(rintf(v[i].x / scale), -QMAXF), QMAXF);
        float q1 = fminf(fmaxf(rintf(v[i].y / scale), -QMAXF), QMAXF);
        float q2 = fminf(fmaxf(rintf(v[i].z / scale), -QMAXF), QMAXF);
        float q3 = fminf(fmaxf(rintf(v[i].w / scale), -QMAXF), QMAXF);
        uint2 p;
        p.x = (unsigned int)f2bf(q0 * scale) | ((unsigned int)f2bf(q1 * scale) << 16);
        p.y = (unsigned int)f2bf(q2 * scale) | ((unsigned int)f2bf(q3 * scale) << 16);
        *reinterpret_cast<uint2*>(wdq + base + (size_t)row * K + c4 * 4) = p;
    }
}

// ---------------------------------------------------------------------------
// Kernel 3: bf16 GEMM, C[t,o] = sum_k A[t,k]*B[o,k] + bias[o].
// 256x256 tile, BK=32, 8 waves (2Mx4N), ring-4 LDS double..quad buffer,
// counted vmcnt (never 0 in main loop), XOR bank swizzle, setprio, XCD swizzle.
// ---------------------------------------------------------------------------
#define GBM 256
#define GBN 256
#define GBK 32
#define RING 4
#define TILE_SH (GBM * GBK)   // 8192 shorts = 16 KiB per matrix per slot
#define SLOT_SH (2 * TILE_SH) // A + B

#define WAITV(n) asm volatile("s_waitcnt vmcnt(" #n ")" ::: "memory")
#define WAITL0() asm volatile("s_waitcnt lgkmcnt(0)" ::: "memory")
#define BARRIER()                          \
    do {                                   \
        asm volatile("" ::: "memory");     \
        __builtin_amdgcn_s_barrier();      \
        asm volatile("" ::: "memory");     \
    } while (0)
#define SCHEDB() __builtin_amdgcn_sched_barrier(0)

__global__ __launch_bounds__(512, 2) void gemm256_kernel(
    const unsigned short* __restrict__ A,   // [M,K] bf16 bits
    const unsigned short* __restrict__ Bw,  // [N,K] bf16 bits
    const float* __restrict__ bias,
    float* __restrict__ C,                  // [M,N] f32
    int M, int N, int K) {
    __shared__ alignas(16) unsigned short lds[RING * SLOT_SH];  // 128 KiB

    int nTn = N / GBN;
    int nwg = gridDim.x;
    int wg = blockIdx.x;
    int swz = (nwg & 7) ? wg : ((wg & 7) * (nwg >> 3) + (wg >> 3));  // bijective: nwg%8==0
    int mt = swz / nTn;
    int nt = swz - mt * nTn;

    int t = threadIdx.x;
    int wid = t >> 6, lane = t & 63;
    int wm = wid >> 2, wn = wid & 3;   // 2 x 4 wave grid
    int lr = lane & 15, lq = lane >> 4;

    const unsigned short* Abase = A + (size_t)mt * GBM * K;
    const unsigned short* Bbase = Bw + (size_t)nt * GBN * K;

    // Staging: thread t covers physical 16B chunks p0 = t and p1 = 512+t of a
    // 256x32 tile (1024 chunks). Physical chunk p holds logical (row = p>>2,
    // chunk c = (p&3) ^ ((row>>1)&3)) -- inverse-swizzled global source so the
    // linear global_load_lds dest yields the swizzled LDS layout (rule 21).
    int p0 = t, p1 = 512 + t;
    int r0 = p0 >> 2, r1 = p1 >> 2;
    int c0 = (p0 & 3) ^ ((r0 >> 1) & 3);
    int c1 = (p1 & 3) ^ ((r1 >> 1) & 3);
    const unsigned short* gA0 = Abase + (size_t)r0 * K + c0 * 8;
    const unsigned short* gA1 = Abase + (size_t)r1 * K + c1 * 8;
    const unsigned short* gB0 = Bbase + (size_t)r0 * K + c0 * 8;
    const unsigned short* gB1 = Bbase + (size_t)r1 * K + c1 * 8;

    // Fragment read offsets (shorts), swizzled to match: phys chunk of
    // (row, kchunk=lq) is row*4 + (lq ^ ((row>>1)&3)).
    int offA[8], offB[4];
#pragma unroll
    for (int m = 0; m < 8; m++) {
        int row = wm * 128 + m * 16 + lr;
        offA[m] = (row * 4 + (lq ^ ((row >> 1) & 3))) * 8;
    }
#pragma unroll
    for (int n = 0; n < 4; n++) {
        int row = wn * 64 + n * 16 + lr;
        offB[n] = TILE_SH + (row * 4 + (lq ^ ((row >> 1) & 3))) * 8;
    }

    f32x4 acc[8][4];
#pragma unroll
    for (int m = 0; m < 8; m++)
#pragma unroll
        for (int n = 0; n < 4; n++) acc[m][n] = (f32x4){0.f, 0.f, 0.f, 0.f};

    int NT = K / GBK;  // 128

    auto STAGE = [&](int ring) {
        unsigned short* s = &lds[ring * SLOT_SH];
        gload_lds16(gA0, s + p0 * 8);
        gload_lds16(gA1, s + p1 * 8);
        gload_lds16(gB0, s + TILE_SH + p0 * 8);
        gload_lds16(gB1, s + TILE_SH + p1 * 8);
        gA0 += GBK; gA1 += GBK; gB0 += GBK; gB1 += GBK;
    };

    auto COMPUTE = [&](int ring) {
        int base = ring * SLOT_SH;
        bf16x8 af[8], bv[4];
#pragma unroll
        for (int n = 0; n < 4; n++)
            bv[n] = *reinterpret_cast<const bf16x8*>(&lds[base + offB[n]]);
#pragma unroll
        for (int m = 0; m < 8; m++)
            af[m] = *reinterpret_cast<const bf16x8*>(&lds[base + offA[m]]);
#pragma unroll
        for (int m = 0; m < 8; m++)
#pragma unroll
            for (int n = 0; n < 4; n++)
                acc[m][n] = __builtin_amdgcn_mfma_f32_16x16x32_bf16(af[m], bv[n],
                                                                    acc[m][n], 0, 0, 0);
    };

    // Prologue: stage tiles 0,1,2 (12 loads in flight).
    STAGE(0);
    STAGE(1);
    STAGE(2);

    // Main loop: stage t+3, wait vmcnt(12) => tile t resident, barrier, compute.
    // Loads for t+1..t+3 (12) stay in flight across the barriers.
    for (int kt = 0; kt < NT - 3; ++kt) {
        STAGE((kt + 3) & 3);
        WAITV(12);
        BARRIER();
        SCHEDB();
        __builtin_amdgcn_s_setprio(1);
        COMPUTE(kt & 3);
        __builtin_amdgcn_s_setprio(0);
        SCHEDB();
        WAITL0();
        BARRIER();
    }
    // Tail: peel with shrinking counted waits.
    WAITV(8);
    BARRIER();
    SCHEDB();
    COMPUTE((NT - 3) & 3);
    SCHEDB();
    WAITL0();
    BARRIER();
    WAITV(4);
    BARRIER();
    SCHEDB();
    COMPUTE((NT - 2) & 3);
    SCHEDB();
    WAITL0();
    BARRIER();
    WAITV(0);
    BARRIER();
    SCHEDB();
    COMPUTE((NT - 1) & 3);

    // Epilogue: bias + store. C/D layout: col = lane&15, row = (lane>>4)*4 + reg.
    float bvv[4];
#pragma unroll
    for (int n = 0; n < 4; n++) bvv[n] = bias[nt * GBN + wn * 64 + n * 16 + lr];

#pragma unroll
    for (int m = 0; m < 8; m++) {
#pragma unroll
        for (int r = 0; r < 4; r++) {
            size_t row = (size_t)(mt * GBM + wm * 128 + m * 16 + lq * 4 + r);
            float* Crow = C + row * N + nt * GBN + wn * 64 + lr;
#pragma unroll
            for (int n = 0; n < 4; n++) Crow[n * 16] = acc[m][n][r] + bvv[n];
        }
    }
}

extern "C" void kernel_launch(void* const* d_in, const int* in_sizes, int n_in,
                              void* d_out, int out_size, void* d_ws, size_t ws_size,
                              hipStream_t stream) {
    const float* x = (const float*)d_in[0];
    const float* w = (const float*)d_in[1];
    const float* bias = (const float*)d_in[2];
    float* y = (float*)d_out;

    int O = in_sizes[2];          // 11008
    int K = in_sizes[1] / O;      // 4096
    int T = in_sizes[0] / K;      // 8192 tokens

    unsigned short* xdq = (unsigned short*)d_ws;
    size_t xbytes = ((size_t)T * K * 2 + 255) & ~(size_t)255;
    unsigned short* wdq = (unsigned short*)((char*)d_ws + xbytes);

    long ngroups = (long)T * (K / 128);
    qd_x_kernel<<<dim3((unsigned)((ngroups + 3) / 4)), dim3(256), 0, stream>>>(x, xdq, ngroups);
    qd_w_kernel<<<dim3(K / 128, O / 128), dim3(256), 0, stream>>>(w, wdq, K);

    int grid = (T / GBM) * (O / GBN);
    gemm256_kernel<<<dim3(grid), dim3(512), 0, stream>>>(xdq, wdq, bias, y, T, O, K);
}

// Round 3
// 763.100 us; speedup vs baseline: 1.5398x; 1.1361x over previous
//
#include <hip/hip_runtime.h>
#include <hip/hip_bf16.h>
#include <stdint.h>

#define QMAXF 127.0f

typedef __attribute__((ext_vector_type(8))) short bf16x8;
typedef __attribute__((ext_vector_type(4))) float f32x4;

typedef __attribute__((address_space(1))) void gbl_void;
typedef __attribute__((address_space(3))) void lds_void;

__device__ __forceinline__ void gload_lds16(const void* g, void* l) {
    __builtin_amdgcn_global_load_lds((const gbl_void*)g, (lds_void*)l, 16, 0, 0);
}

// Exact RNE float->bf16 (finite inputs only, which holds here).
__device__ __forceinline__ unsigned short f2bf(float f) {
    unsigned int u = __builtin_bit_cast(unsigned int, f);
    unsigned int r = (u + 0x7fffu + ((u >> 16) & 1u)) >> 16;
    return (unsigned short)r;
}

// ---------------------------------------------------------------------------
// Kernel 1: per-token, per-128-col-group quant-dequant of activations.
// ---------------------------------------------------------------------------
__global__ __launch_bounds__(256) void qd_x_kernel(const float* __restrict__ x,
                                                   unsigned short* __restrict__ xdq,
                                                   long ngroups) {
    long gw = ((long)blockIdx.x * blockDim.x + threadIdx.x) >> 6;
    int lane = threadIdx.x & 63;
    if (gw >= ngroups) return;

    float2 v = *(reinterpret_cast<const float2*>(x) + gw * 64 + lane);
    float a = fmaxf(fabsf(v.x), fabsf(v.y));
#pragma unroll
    for (int off = 32; off; off >>= 1) a = fmaxf(a, __shfl_xor(a, off));

    float scale = a > 0.f ? a / QMAXF : 1.f;
    float qx = fminf(fmaxf(rintf(v.x / scale), -QMAXF), QMAXF);
    float qy = fminf(fmaxf(rintf(v.y / scale), -QMAXF), QMAXF);
    unsigned int packed = (unsigned int)f2bf(qx * scale) | ((unsigned int)f2bf(qy * scale) << 16);
    reinterpret_cast<unsigned int*>(xdq)[gw * 64 + lane] = packed;
}

// ---------------------------------------------------------------------------
// Kernel 2: 128x128 blockwise quant-dequant of weights.
// ---------------------------------------------------------------------------
__global__ __launch_bounds__(256) void qd_w_kernel(const float* __restrict__ w,
                                                   unsigned short* __restrict__ wdq,
                                                   int K) {
    int kb = blockIdx.x, ob = blockIdx.y;
    size_t base = (size_t)ob * 128 * K + (size_t)kb * 128;
    int t = threadIdx.x;

    float4 v[16];
    float a = 0.f;
#pragma unroll
    for (int i = 0; i < 16; i++) {
        int f = i * 256 + t;
        int row = f >> 5, c4 = f & 31;
        v[i] = *reinterpret_cast<const float4*>(w + base + (size_t)row * K + c4 * 4);
        a = fmaxf(a, fmaxf(fmaxf(fabsf(v[i].x), fabsf(v[i].y)),
                           fmaxf(fabsf(v[i].z), fabsf(v[i].w))));
    }
#pragma unroll
    for (int off = 32; off; off >>= 1) a = fmaxf(a, __shfl_xor(a, off));

    __shared__ float red[4];
    if ((t & 63) == 0) red[t >> 6] = a;
    __syncthreads();
    a = fmaxf(fmaxf(red[0], red[1]), fmaxf(red[2], red[3]));

    float scale = a > 0.f ? a / QMAXF : 1.f;
#pragma unroll
    for (int i = 0; i < 16; i++) {
        int f = i * 256 + t;
        int row = f >> 5, c4 = f & 31;
        float q0 = fminf(fmaxf(rintf(v[i].x / scale), -QMAXF), QMAXF);
        float q1 = fminf(fmaxf(rintf(v[i].y / scale), -QMAXF), QMAXF);
        float q2 = fminf(fmaxf(rintf(v[i].z / scale), -QMAXF), QMAXF);
        float q3 = fminf(fmaxf(rintf(v[i].w / scale), -QMAXF), QMAXF);
        uint2 p;
        p.x = (unsigned int)f2bf(q0 * scale) | ((unsigned int)f2bf(q1 * scale) << 16);
        p.y = (unsigned int)f2bf(q2 * scale) | ((unsigned int)f2bf(q3 * scale) << 16);
        *reinterpret_cast<uint2*>(wdq + base + (size_t)row * K + c4 * 4) = p;
    }
}

// ---------------------------------------------------------------------------
// Kernel 3: bf16 GEMM, 256x256 tile, BK=64, 8-phase schedule (m201 template):
// per phase {ds-read subtile || stage 1 half-tile -> barrier -> lgkmcnt(0) ->
// setprio+16 MFMA -> barrier}, counted vmcnt(4) at phases 4/8 only.
// Stage/read liveness: slot1.A @ph1-2, slot0.B @ph3-4, slot0.A @ph5-6,
// slot1.B @ph7-8; each half staged strictly after its last reader phase.
// ---------------------------------------------------------------------------
#define GBM 256
#define GBN 256
#define GBK 64
#define TILE_SH (GBM * GBK)      // 16384 shorts = 32 KiB per matrix per slot
#define SLOT_SH (2 * TILE_SH)    // A + B

#define BAR()                              \
    do {                                   \
        asm volatile("" ::: "memory");     \
        __builtin_amdgcn_s_barrier();      \
        asm volatile("" ::: "memory");     \
    } while (0)
#define WAITL0()                                          \
    do {                                                  \
        asm volatile("s_waitcnt lgkmcnt(0)" ::: "memory");\
        __builtin_amdgcn_sched_barrier(0);                \
    } while (0)
#define WAITV4() asm volatile("s_waitcnt vmcnt(4)" ::: "memory")

__global__ __launch_bounds__(512, 1) void gemm8p_kernel(
    const unsigned short* __restrict__ A,   // [M,K] bf16 bits
    const unsigned short* __restrict__ Bw,  // [N,K] bf16 bits
    const float* __restrict__ bias,
    float* __restrict__ C,                  // [M,N] f32
    int M, int N, int K) {
    __shared__ alignas(16) unsigned short lds[2 * SLOT_SH];  // 128 KiB

    int nTn = N / GBN;
    int nwg = gridDim.x, wg = blockIdx.x;
    int swz = (nwg & 7) ? wg : ((wg & 7) * (nwg >> 3) + (wg >> 3));  // bijective: nwg%8==0
    int mt = swz / nTn;
    int nt = swz - mt * nTn;

    int t = threadIdx.x, wid = t >> 6, lane = t & 63;
    int wm = wid >> 2, wn = wid & 3;   // 2 x 4 wave grid; wave tile 128x64
    int lr = lane & 15, lq = lane >> 4;

    const unsigned short* Abase = A + (size_t)mt * GBM * K;
    const unsigned short* Bbase = Bw + (size_t)nt * GBN * K;

    // Staging geometry: half-tile = 128 rows x 64 cols (8 chunks of 16B/row).
    // Thread t covers phys chunks t and 512+t: rows r0, r0+64, phys chunk pc.
    // Swizzle (involution): logical chunk = pc ^ (row & 7); 64 === 0 mod 8 so
    // both rows share c0.
    int r0 = t >> 3;
    int pc = t & 7;
    int c0 = pc ^ (r0 & 7);
    const unsigned short* Aln = Abase + (size_t)r0 * K + c0 * 8;
    const unsigned short* Bln = Bbase + (size_t)r0 * K + c0 * 8;

    // Stage half `half` of matrix `mat` (0=A,1=B) of slot `slot` at k-offset kb.
    auto STAGE = [&](int slot, int mat, int half, int kb) {
        const unsigned short* g = (mat ? Bln : Aln) + (size_t)half * 128 * K + kb;
        unsigned short* d = &lds[slot * SLOT_SH + mat * TILE_SH + (half * 1024 + t) * 8];
        gload_lds16(g, d);
        gload_lds16(g + (size_t)64 * K, d + 512 * 8);
    };

    // Fragment ds_read offsets (shorts). Row of frag (m,kk): wm*128+m*16+lr
    // (A) / wn*64+n*16+lr (B); chunk = kk*4+lq, phys = chunk ^ (row&7) and
    // row&7 == lr&7 for all fragment rows. mq adds 64 rows (4096 sh), nq 32
    // rows (2048 sh) -- both preserve row&7.
    int xo0 = lq ^ (lr & 7);
    int xo1 = (4 + lq) ^ (lr & 7);
    int offA[4][2], offB[2][2];
#pragma unroll
    for (int m = 0; m < 4; m++) {
        int row = wm * 128 + m * 16 + lr;
        offA[m][0] = (row * 8 + xo0) * 8;
        offA[m][1] = (row * 8 + xo1) * 8;
    }
#pragma unroll
    for (int n = 0; n < 2; n++) {
        int row = wn * 64 + n * 16 + lr;
        offB[n][0] = TILE_SH + (row * 8 + xo0) * 8;
        offB[n][1] = TILE_SH + (row * 8 + xo1) * 8;
    }

    f32x4 acc[8][4];
#pragma unroll
    for (int m = 0; m < 8; m++)
#pragma unroll
        for (int n = 0; n < 4; n++) acc[m][n] = (f32x4){0.f, 0.f, 0.f, 0.f};

    bf16x8 ar[8], b0[4], b1[4];

    auto LDA = [&](int slot, int mq) {
        int base = slot * SLOT_SH + mq * 4096;
#pragma unroll
        for (int m = 0; m < 4; m++)
#pragma unroll
            for (int kk = 0; kk < 2; kk++)
                ar[m * 2 + kk] = *reinterpret_cast<const bf16x8*>(&lds[base + offA[m][kk]]);
    };
    auto LDB = [&](int slot, int nq, bf16x8* b) {
        int base = slot * SLOT_SH + nq * 2048;
#pragma unroll
        for (int n = 0; n < 2; n++)
#pragma unroll
            for (int kk = 0; kk < 2; kk++)
                b[n * 2 + kk] = *reinterpret_cast<const bf16x8*>(&lds[base + offB[n][kk]]);
    };
    auto MMA = [&](int mq, int nq, bf16x8* b) {
        __builtin_amdgcn_s_setprio(1);
#pragma unroll
        for (int m = 0; m < 4; m++)
#pragma unroll
            for (int n = 0; n < 2; n++)
#pragma unroll
                for (int kk = 0; kk < 2; kk++)
                    acc[mq * 4 + m][nq * 2 + n] = __builtin_amdgcn_mfma_f32_16x16x32_bf16(
                        ar[m * 2 + kk], b[n * 2 + kk], acc[mq * 4 + m][nq * 2 + n], 0, 0, 0);
        __builtin_amdgcn_s_setprio(0);
    };

    int NTm1 = K / GBK - 1;   // 63
    int NI = (K / GBK) / 2;   // 32

    // Prologue: slot0 <- K-tile 0 (4 halves), slot1.B <- K-tile 1 (2 halves).
    STAGE(0, 0, 0, 0);
    STAGE(0, 0, 1, 0);
    STAGE(0, 1, 0, 0);
    STAGE(0, 1, 1, 0);
    STAGE(1, 1, 0, GBK);
    STAGE(1, 1, 1, GBK);
    WAITV4();   // slot0's 8 loads returned; slot1.B (4) may fly
    BAR();

    for (int i = 0; i < NI; ++i) {
        int kb1 = min(2 * i + 1, NTm1) * GBK;  // tau1 (slot1 A)
        int kb2 = min(2 * i + 2, NTm1) * GBK;  // tau0+2 (slot0 restage)
        int kb3 = min(2 * i + 3, NTm1) * GBK;  // tau1+2 (slot1 B restage)

        // ph1: compute slot0 Q(0,0); stage slot1.A.h0 (tau1)
        LDA(0, 0); LDB(0, 0, b0);
        STAGE(1, 0, 0, kb1);
        BAR(); WAITL0();
        MMA(0, 0, b0);
        BAR();
        // ph2: Q(0,1); stage slot1.A.h1
        LDB(0, 1, b1);
        STAGE(1, 0, 1, kb1);
        BAR(); WAITL0();
        MMA(0, 1, b1);
        BAR();
        // ph3: Q(1,0); stage slot0.B.h0 (tau0+2; slot0.B dead after ph2)
        LDA(0, 1);
        STAGE(0, 1, 0, kb2);
        BAR(); WAITL0();
        MMA(1, 0, b0);
        BAR();
        // ph4: Q(1,1); stage slot0.B.h1; counted vmcnt -> slot1 tile resident
        STAGE(0, 1, 1, kb2);
        BAR();
        __builtin_amdgcn_sched_barrier(0);
        MMA(1, 1, b1);
        WAITV4();
        BAR();
        // ph5: compute slot1 Q(0,0); stage slot0.A.h0 (slot0.A dead after ph3)
        LDA(1, 0); LDB(1, 0, b0);
        STAGE(0, 0, 0, kb2);
        BAR(); WAITL0();
        MMA(0, 0, b0);
        BAR();
        // ph6: Q(0,1); stage slot0.A.h1
        LDB(1, 1, b1);
        STAGE(0, 0, 1, kb2);
        BAR(); WAITL0();
        MMA(0, 1, b1);
        BAR();
        // ph7: Q(1,0); stage slot1.B.h0 (tau1+2; slot1.B dead after ph6)
        LDA(1, 1);
        STAGE(1, 1, 0, kb3);
        BAR(); WAITL0();
        MMA(1, 0, b0);
        BAR();
        // ph8: Q(1,1); stage slot1.B.h1; counted vmcnt -> slot0 tile resident
        STAGE(1, 1, 1, kb3);
        BAR();
        __builtin_amdgcn_sched_barrier(0);
        MMA(1, 1, b1);
        WAITV4();
        BAR();
    }

    // Epilogue: bias + store. C/D layout: col = lane&15, row = (lane>>4)*4 + reg.
    float bvv[4];
#pragma unroll
    for (int n = 0; n < 4; n++) bvv[n] = bias[nt * GBN + wn * 64 + n * 16 + lr];

#pragma unroll
    for (int m = 0; m < 8; m++) {
#pragma unroll
        for (int r = 0; r < 4; r++) {
            size_t row = (size_t)(mt * GBM + wm * 128 + m * 16 + lq * 4 + r);
            float* Crow = C + row * N + nt * GBN + wn * 64 + lr;
#pragma unroll
            for (int n = 0; n < 4; n++) Crow[n * 16] = acc[m][n][r] + bvv[n];
        }
    }
}

extern "C" void kernel_launch(void* const* d_in, const int* in_sizes, int n_in,
                              void* d_out, int out_size, void* d_ws, size_t ws_size,
                              hipStream_t stream) {
    const float* x = (const float*)d_in[0];
    const float* w = (const float*)d_in[1];
    const float* bias = (const float*)d_in[2];
    float* y = (float*)d_out;

    int O = in_sizes[2];          // 11008
    int K = in_sizes[1] / O;      // 4096
    int T = in_sizes[0] / K;      // 8192 tokens

    unsigned short* xdq = (unsigned short*)d_ws;
    size_t xbytes = ((size_t)T * K * 2 + 255) & ~(size_t)255;
    unsigned short* wdq = (unsigned short*)((char*)d_ws + xbytes);

    long ngroups = (long)T * (K / 128);
    qd_x_kernel<<<dim3((unsigned)((ngroups + 3) / 4)), dim3(256), 0, stream>>>(x, xdq, ngroups);
    qd_w_kernel<<<dim3(K / 128, O / 128), dim3(256), 0, stream>>>(w, wdq, K);

    int grid = (T / GBM) * (O / GBN);
    gemm8p_kernel<<<dim3(grid), dim3(512), 0, stream>>>(xdq, wdq, bias, y, T, O, K);
}

// Round 4
// 762.982 us; speedup vs baseline: 1.5401x; 1.0002x over previous
//
#include <hip/hip_runtime.h>
#include <hip/hip_bf16.h>
#include <stdint.h>

#define QMAXF 127.0f

typedef __attribute__((ext_vector_type(8))) short bf16x8;
typedef __attribute__((ext_vector_type(4))) float f32x4;

typedef __attribute__((address_space(1))) void gbl_void;
typedef __attribute__((address_space(3))) void lds_void;

__device__ __forceinline__ void gload_lds16(const void* g, void* l) {
    __builtin_amdgcn_global_load_lds((const gbl_void*)g, (lds_void*)l, 16, 0, 0);
}

// Exact RNE float->bf16 (finite inputs only, which holds here).
__device__ __forceinline__ unsigned short f2bf(float f) {
    unsigned int u = __builtin_bit_cast(unsigned int, f);
    unsigned int r = (u + 0x7fffu + ((u >> 16) & 1u)) >> 16;
    return (unsigned short)r;
}

// ---------------------------------------------------------------------------
// Kernel 1: per-token, per-128-col-group quant-dequant of activations.
// ---------------------------------------------------------------------------
__global__ __launch_bounds__(256) void qd_x_kernel(const float* __restrict__ x,
                                                   unsigned short* __restrict__ xdq,
                                                   long ngroups) {
    long gw = ((long)blockIdx.x * blockDim.x + threadIdx.x) >> 6;
    int lane = threadIdx.x & 63;
    if (gw >= ngroups) return;

    float2 v = *(reinterpret_cast<const float2*>(x) + gw * 64 + lane);
    float a = fmaxf(fabsf(v.x), fabsf(v.y));
#pragma unroll
    for (int off = 32; off; off >>= 1) a = fmaxf(a, __shfl_xor(a, off));

    float scale = a > 0.f ? a / QMAXF : 1.f;
    float qx = fminf(fmaxf(rintf(v.x / scale), -QMAXF), QMAXF);
    float qy = fminf(fmaxf(rintf(v.y / scale), -QMAXF), QMAXF);
    unsigned int packed = (unsigned int)f2bf(qx * scale) | ((unsigned int)f2bf(qy * scale) << 16);
    reinterpret_cast<unsigned int*>(xdq)[gw * 64 + lane] = packed;
}

// ---------------------------------------------------------------------------
// Kernel 2: 128x128 blockwise quant-dequant of weights.
// ---------------------------------------------------------------------------
__global__ __launch_bounds__(256) void qd_w_kernel(const float* __restrict__ w,
                                                   unsigned short* __restrict__ wdq,
                                                   int K) {
    int kb = blockIdx.x, ob = blockIdx.y;
    size_t base = (size_t)ob * 128 * K + (size_t)kb * 128;
    int t = threadIdx.x;

    float4 v[16];
    float a = 0.f;
#pragma unroll
    for (int i = 0; i < 16; i++) {
        int f = i * 256 + t;
        int row = f >> 5, c4 = f & 31;
        v[i] = *reinterpret_cast<const float4*>(w + base + (size_t)row * K + c4 * 4);
        a = fmaxf(a, fmaxf(fmaxf(fabsf(v[i].x), fabsf(v[i].y)),
                           fmaxf(fabsf(v[i].z), fabsf(v[i].w))));
    }
#pragma unroll
    for (int off = 32; off; off >>= 1) a = fmaxf(a, __shfl_xor(a, off));

    __shared__ float red[4];
    if ((t & 63) == 0) red[t >> 6] = a;
    __syncthreads();
    a = fmaxf(fmaxf(red[0], red[1]), fmaxf(red[2], red[3]));

    float scale = a > 0.f ? a / QMAXF : 1.f;
#pragma unroll
    for (int i = 0; i < 16; i++) {
        int f = i * 256 + t;
        int row = f >> 5, c4 = f & 31;
        float q0 = fminf(fmaxf(rintf(v[i].x / scale), -QMAXF), QMAXF);
        float q1 = fminf(fmaxf(rintf(v[i].y / scale), -QMAXF), QMAXF);
        float q2 = fminf(fmaxf(rintf(v[i].z / scale), -QMAXF), QMAXF);
        float q3 = fminf(fmaxf(rintf(v[i].w / scale), -QMAXF), QMAXF);
        uint2 p;
        p.x = (unsigned int)f2bf(q0 * scale) | ((unsigned int)f2bf(q1 * scale) << 16);
        p.y = (unsigned int)f2bf(q2 * scale) | ((unsigned int)f2bf(q3 * scale) << 16);
        *reinterpret_cast<uint2*>(wdq + base + (size_t)row * K + c4 * 4) = p;
    }
}

// ---------------------------------------------------------------------------
// Kernel 3: bf16 GEMM, 256x256 tile, BK=64, 8-phase PREFETCHED schedule:
// per phase {lgkm-wait (prev prefetch, free) -> issue next-phase ds_reads +
// 1 half-tile stage -> setprio + 16 MFMA on regs loaded last phase -> barrier}.
// Counted vmcnt(2) at end of ph3/ph7 publishes the slot the NEXT phase
// prefetch-reads. Liveness verified pairwise (reads published before
// restage; stages vmcnt-forced before first read).
// ---------------------------------------------------------------------------
#define GBM 256
#define GBN 256
#define GBK 64
#define TILE_SH (GBM * GBK)      // 16384 shorts = 32 KiB per matrix per slot
#define SLOT_SH (2 * TILE_SH)    // A + B

#define BAR()                              \
    do {                                   \
        asm volatile("" ::: "memory");     \
        __builtin_amdgcn_s_barrier();      \
        asm volatile("" ::: "memory");     \
    } while (0)
#define WAITL0()                                          \
    do {                                                  \
        asm volatile("s_waitcnt lgkmcnt(0)" ::: "memory");\
        __builtin_amdgcn_sched_barrier(0);                \
    } while (0)
#define WAITV(n) asm volatile("s_waitcnt vmcnt(" #n ")" ::: "memory")
#define SCHED0() __builtin_amdgcn_sched_barrier(0)

__global__ __launch_bounds__(512, 1) void gemm8p_kernel(
    const unsigned short* __restrict__ A,   // [M,K] bf16 bits
    const unsigned short* __restrict__ Bw,  // [N,K] bf16 bits
    const float* __restrict__ bias,
    float* __restrict__ C,                  // [M,N] f32
    int M, int N, int K) {
    __shared__ alignas(16) unsigned short lds[2 * SLOT_SH];  // 128 KiB

    int nTn = N / GBN;
    int nwg = gridDim.x, wg = blockIdx.x;
    int swz = (nwg & 7) ? wg : ((wg & 7) * (nwg >> 3) + (wg >> 3));  // bijective: nwg%8==0
    int mt = swz / nTn;
    int nt = swz - mt * nTn;

    int t = threadIdx.x, wid = t >> 6, lane = t & 63;
    int wm = wid >> 2, wn = wid & 3;   // 2 x 4 wave grid; wave tile 128x64
    int lr = lane & 15, lq = lane >> 4;

    const unsigned short* Abase = A + (size_t)mt * GBM * K;
    const unsigned short* Bbase = Bw + (size_t)nt * GBN * K;

    // Staging: thread t covers rows r0, r0+64 at phys chunk pc; involution
    // swizzle logical chunk = pc ^ (row & 7) (64 === 0 mod 8: both rows share c0).
    int r0 = t >> 3;
    int pc = t & 7;
    int c0 = pc ^ (r0 & 7);
    const unsigned short* Aln = Abase + (size_t)r0 * K + c0 * 8;
    const unsigned short* Bln = Bbase + (size_t)r0 * K + c0 * 8;

    auto STAGE = [&](int slot, int mat, int half, int kb) {
        const unsigned short* g = (mat ? Bln : Aln) + (size_t)half * 128 * K + kb;
        unsigned short* d = &lds[slot * SLOT_SH + mat * TILE_SH + (half * 1024 + t) * 8];
        gload_lds16(g, d);
        gload_lds16(g + (size_t)64 * K, d + 512 * 8);
    };

    // Fragment ds_read offsets (shorts): phys chunk = (kk*4+lq) ^ (row&7),
    // row&7 == lr&7 for all fragment rows.
    int xo0 = lq ^ (lr & 7);
    int xo1 = (4 + lq) ^ (lr & 7);
    int offA[4][2], offB[2][2];
#pragma unroll
    for (int m = 0; m < 4; m++) {
        int row = wm * 128 + m * 16 + lr;
        offA[m][0] = (row * 8 + xo0) * 8;
        offA[m][1] = (row * 8 + xo1) * 8;
    }
#pragma unroll
    for (int n = 0; n < 2; n++) {
        int row = wn * 64 + n * 16 + lr;
        offB[n][0] = TILE_SH + (row * 8 + xo0) * 8;
        offB[n][1] = TILE_SH + (row * 8 + xo1) * 8;
    }

    f32x4 acc[8][4];
#pragma unroll
    for (int m = 0; m < 8; m++)
#pragma unroll
        for (int n = 0; n < 4; n++) acc[m][n] = (f32x4){0.f, 0.f, 0.f, 0.f};

    // Double register sets: arE (A quad mq=0), arO (mq=1), b0 (nq=0), b1 (nq=1).
    bf16x8 arE[8], arO[8], b0[4], b1[4];

    auto LD_A = [&](int slot, int mq, bf16x8* ar) {
        int base = slot * SLOT_SH + mq * 4096;
#pragma unroll
        for (int m = 0; m < 4; m++)
#pragma unroll
            for (int kk = 0; kk < 2; kk++)
                ar[m * 2 + kk] = *reinterpret_cast<const bf16x8*>(&lds[base + offA[m][kk]]);
    };
    auto LD_B = [&](int slot, int nq, bf16x8* b) {
        int base = slot * SLOT_SH + nq * 2048;
#pragma unroll
        for (int n = 0; n < 2; n++)
#pragma unroll
            for (int kk = 0; kk < 2; kk++)
                b[n * 2 + kk] = *reinterpret_cast<const bf16x8*>(&lds[base + offB[n][kk]]);
    };
    auto MMA = [&](int mq, int nq, bf16x8* ar, bf16x8* b) {
        __builtin_amdgcn_s_setprio(1);
#pragma unroll
        for (int m = 0; m < 4; m++)
#pragma unroll
            for (int n = 0; n < 2; n++)
#pragma unroll
                for (int kk = 0; kk < 2; kk++)
                    acc[mq * 4 + m][nq * 2 + n] = __builtin_amdgcn_mfma_f32_16x16x32_bf16(
                        ar[m * 2 + kk], b[n * 2 + kk], acc[mq * 4 + m][nq * 2 + n], 0, 0, 0);
        __builtin_amdgcn_s_setprio(0);
    };

    int NTm1 = K / GBK - 1;   // 63
    int NI = (K / GBK) / 2;   // 32

    // Prologue: slot0 full (8 loads), slot1.B (4 loads); preload ph1 regs.
    STAGE(0, 0, 0, 0);
    STAGE(0, 0, 1, 0);
    STAGE(0, 1, 0, 0);
    STAGE(0, 1, 1, 0);
    STAGE(1, 1, 0, GBK);
    STAGE(1, 1, 1, GBK);
    WAITV(4);   // slot0 resident; slot1.B (4) may fly
    BAR();
    LD_A(0, 0, arE);
    LD_B(0, 0, b0);

    for (int i = 0; i < NI; ++i) {
        int kb1 = min(2 * i + 1, NTm1) * GBK;  // slot1.A (real tile tau1)
        int kb2 = min(2 * i + 2, NTm1) * GBK;  // slot0 restage
        int kb3 = min(2 * i + 3, NTm1) * GBK;  // slot1.B restage

        // ph1: MMA slot0 Q(0,0); prefetch b1<-slot0.B1; stage s1A.h0
        WAITL0();
        LD_B(0, 1, b1);
        STAGE(1, 0, 0, kb1);
        SCHED0();
        MMA(0, 0, arE, b0);
        BAR();
        // ph2: Q(0,1); prefetch arO<-slot0.A1; stage s1A.h1
        WAITL0();
        LD_A(0, 1, arO);
        STAGE(1, 0, 1, kb1);
        SCHED0();
        MMA(0, 1, arE, b1);
        BAR();
        // ph3: Q(1,0); stage s0B.h0; vmcnt(2) forces slot1.A + prev slot1.B resident
        WAITL0();
        STAGE(0, 1, 0, kb2);
        SCHED0();
        MMA(1, 0, arO, b0);
        WAITV(2);
        BAR();
        // ph4: Q(1,1); prefetch arE<-slot1.A0, b0<-slot1.B0; stage s0B.h1
        WAITL0();
        LD_A(1, 0, arE);
        LD_B(1, 0, b0);
        STAGE(0, 1, 1, kb2);
        SCHED0();
        MMA(1, 1, arO, b1);
        BAR();
        // ph5: slot1 Q(0,0); prefetch b1<-slot1.B1; stage s0A.h0
        WAITL0();
        LD_B(1, 1, b1);
        STAGE(0, 0, 0, kb2);
        SCHED0();
        MMA(0, 0, arE, b0);
        BAR();
        // ph6: Q(0,1); prefetch arO<-slot1.A1; stage s0A.h1
        WAITL0();
        LD_A(1, 1, arO);
        STAGE(0, 0, 1, kb2);
        SCHED0();
        MMA(0, 1, arE, b1);
        BAR();
        // ph7: Q(1,0); stage s1B.h0; vmcnt(2) forces restaged slot0 resident
        WAITL0();
        STAGE(1, 1, 0, kb3);
        SCHED0();
        MMA(1, 0, arO, b0);
        WAITV(2);
        BAR();
        // ph8: Q(1,1); prefetch arE<-slot0.A0, b0<-slot0.B0 (next K-pair); stage s1B.h1
        WAITL0();
        LD_A(0, 0, arE);
        LD_B(0, 0, b0);
        STAGE(1, 1, 1, kb3);
        SCHED0();
        MMA(1, 1, arO, b1);
        BAR();
    }

    // Epilogue: bias + store. C/D layout: col = lane&15, row = (lane>>4)*4 + reg.
    float bvv[4];
#pragma unroll
    for (int n = 0; n < 4; n++) bvv[n] = bias[nt * GBN + wn * 64 + n * 16 + lr];

#pragma unroll
    for (int m = 0; m < 8; m++) {
#pragma unroll
        for (int r = 0; r < 4; r++) {
            size_t row = (size_t)(mt * GBM + wm * 128 + m * 16 + lq * 4 + r);
            float* Crow = C + row * N + nt * GBN + wn * 64 + lr;
#pragma unroll
            for (int n = 0; n < 4; n++) Crow[n * 16] = acc[m][n][r] + bvv[n];
        }
    }
}

extern "C" void kernel_launch(void* const* d_in, const int* in_sizes, int n_in,
                              void* d_out, int out_size, void* d_ws, size_t ws_size,
                              hipStream_t stream) {
    const float* x = (const float*)d_in[0];
    const float* w = (const float*)d_in[1];
    const float* bias = (const float*)d_in[2];
    float* y = (float*)d_out;

    int O = in_sizes[2];          // 11008
    int K = in_sizes[1] / O;      // 4096
    int T = in_sizes[0] / K;      // 8192 tokens

    unsigned short* xdq = (unsigned short*)d_ws;
    size_t xbytes = ((size_t)T * K * 2 + 255) & ~(size_t)255;
    unsigned short* wdq = (unsigned short*)((char*)d_ws + xbytes);

    long ngroups = (long)T * (K / 128);
    qd_x_kernel<<<dim3((unsigned)((ngroups + 3) / 4)), dim3(256), 0, stream>>>(x, xdq, ngroups);
    qd_w_kernel<<<dim3(K / 128, O / 128), dim3(256), 0, stream>>>(w, wdq, K);

    int grid = (T / GBM) * (O / GBN);
    gemm8p_kernel<<<dim3(grid), dim3(512), 0, stream>>>(xdq, wdq, bias, y, T, O, K);
}

// Round 5
// 730.195 us; speedup vs baseline: 1.6092x; 1.0449x over previous
//
#include <hip/hip_runtime.h>
#include <hip/hip_bf16.h>
#include <stdint.h>

#define QMAXF 127.0f

typedef __attribute__((ext_vector_type(8))) short bf16x8;
typedef __attribute__((ext_vector_type(4))) float f32x4;

typedef __attribute__((address_space(1))) void gbl_void;
typedef __attribute__((address_space(3))) void lds_void;

__device__ __forceinline__ void gload_lds16(const void* g, void* l) {
    __builtin_amdgcn_global_load_lds((const gbl_void*)g, (lds_void*)l, 16, 0, 0);
}

// Exact RNE float->bf16 (finite inputs only, which holds here).
__device__ __forceinline__ unsigned short f2bf(float f) {
    unsigned int u = __builtin_bit_cast(unsigned int, f);
    unsigned int r = (u + 0x7fffu + ((u >> 16) & 1u)) >> 16;
    return (unsigned short)r;
}

// ---------------------------------------------------------------------------
// Kernel 1: per-token, per-128-col-group quant-dequant of activations.
// ---------------------------------------------------------------------------
__global__ __launch_bounds__(256) void qd_x_kernel(const float* __restrict__ x,
                                                   unsigned short* __restrict__ xdq,
                                                   long ngroups) {
    long gw = ((long)blockIdx.x * blockDim.x + threadIdx.x) >> 6;
    int lane = threadIdx.x & 63;
    if (gw >= ngroups) return;

    float2 v = *(reinterpret_cast<const float2*>(x) + gw * 64 + lane);
    float a = fmaxf(fabsf(v.x), fabsf(v.y));
#pragma unroll
    for (int off = 32; off; off >>= 1) a = fmaxf(a, __shfl_xor(a, off));

    float scale = a > 0.f ? a / QMAXF : 1.f;
    float qx = fminf(fmaxf(rintf(v.x / scale), -QMAXF), QMAXF);
    float qy = fminf(fmaxf(rintf(v.y / scale), -QMAXF), QMAXF);
    unsigned int packed = (unsigned int)f2bf(qx * scale) | ((unsigned int)f2bf(qy * scale) << 16);
    reinterpret_cast<unsigned int*>(xdq)[gw * 64 + lane] = packed;
}

// ---------------------------------------------------------------------------
// Kernel 2: 128x128 blockwise quant-dequant of weights.
// ---------------------------------------------------------------------------
__global__ __launch_bounds__(256) void qd_w_kernel(const float* __restrict__ w,
                                                   unsigned short* __restrict__ wdq,
                                                   int K) {
    int kb = blockIdx.x, ob = blockIdx.y;
    size_t base = (size_t)ob * 128 * K + (size_t)kb * 128;
    int t = threadIdx.x;

    float4 v[16];
    float a = 0.f;
#pragma unroll
    for (int i = 0; i < 16; i++) {
        int f = i * 256 + t;
        int row = f >> 5, c4 = f & 31;
        v[i] = *reinterpret_cast<const float4*>(w + base + (size_t)row * K + c4 * 4);
        a = fmaxf(a, fmaxf(fmaxf(fabsf(v[i].x), fabsf(v[i].y)),
                           fmaxf(fabsf(v[i].z), fabsf(v[i].w))));
    }
#pragma unroll
    for (int off = 32; off; off >>= 1) a = fmaxf(a, __shfl_xor(a, off));

    __shared__ float red[4];
    if ((t & 63) == 0) red[t >> 6] = a;
    __syncthreads();
    a = fmaxf(fmaxf(red[0], red[1]), fmaxf(red[2], red[3]));

    float scale = a > 0.f ? a / QMAXF : 1.f;
#pragma unroll
    for (int i = 0; i < 16; i++) {
        int f = i * 256 + t;
        int row = f >> 5, c4 = f & 31;
        float q0 = fminf(fmaxf(rintf(v[i].x / scale), -QMAXF), QMAXF);
        float q1 = fminf(fmaxf(rintf(v[i].y / scale), -QMAXF), QMAXF);
        float q2 = fminf(fmaxf(rintf(v[i].z / scale), -QMAXF), QMAXF);
        float q3 = fminf(fmaxf(rintf(v[i].w / scale), -QMAXF), QMAXF);
        uint2 p;
        p.x = (unsigned int)f2bf(q0 * scale) | ((unsigned int)f2bf(q1 * scale) << 16);
        p.y = (unsigned int)f2bf(q2 * scale) | ((unsigned int)f2bf(q3 * scale) << 16);
        *reinterpret_cast<uint2*>(wdq + base + (size_t)row * K + c4 * 4) = p;
    }
}

// ---------------------------------------------------------------------------
// Kernel 3: bf16 GEMM, 256x256 tile, BK=64, 8-phase prefetched schedule (R4)
// + 2-level XCD-aware 2D tile window: each XCD owns nTm/8 mt-rows; its 32
// co-resident blocks form a (nTm/8) x (32/(nTm/8)) window so concurrent
// blocks share A- and B-panels in L2 (K-slab working set ~384 KB << 4 MB).
// ---------------------------------------------------------------------------
#define GBM 256
#define GBN 256
#define GBK 64
#define TILE_SH (GBM * GBK)      // 16384 shorts = 32 KiB per matrix per slot
#define SLOT_SH (2 * TILE_SH)    // A + B

#define BAR()                              \
    do {                                   \
        asm volatile("" ::: "memory");     \
        __builtin_amdgcn_s_barrier();      \
        asm volatile("" ::: "memory");     \
    } while (0)
#define WAITL0()                                          \
    do {                                                  \
        asm volatile("s_waitcnt lgkmcnt(0)" ::: "memory");\
        __builtin_amdgcn_sched_barrier(0);                \
    } while (0)
#define WAITV(n) asm volatile("s_waitcnt vmcnt(" #n ")" ::: "memory")
#define SCHED0() __builtin_amdgcn_sched_barrier(0)

__global__ __launch_bounds__(512, 1) void gemm8p_kernel(
    const unsigned short* __restrict__ A,   // [M,K] bf16 bits
    const unsigned short* __restrict__ Bw,  // [N,K] bf16 bits
    const float* __restrict__ bias,
    float* __restrict__ C,                  // [M,N] f32
    int M, int N, int K) {
    __shared__ alignas(16) unsigned short lds[2 * SLOT_SH];  // 128 KiB

    int nTm = M / GBM, nTn = N / GBN;
    int nwg = gridDim.x, wg = blockIdx.x;
    int mt, nt;
    if ((nTm & 7) == 0 && (32 % (nTm >> 3)) == 0) {
        // 2-level XCD window mapping. HW round-robins blockIdx across 8 XCDs,
        // so XCD x runs blocks {wg : wg%8==x} in order j = wg/8. XCD x owns
        // mt rows [x*mper, (x+1)*mper); windows of 32 blocks = mper x G tiles.
        int x = wg & 7, j = wg >> 3;
        int mper = nTm >> 3;            // mt rows per XCD
        int G = 32 / mper;              // nt columns per window
        int wsz = mper * G;             // 32
        int fullw = nTn / G;
        int jfull = fullw * wsz;
        int g, r, width;
        if (j < jfull) { g = j / wsz; r = j - g * wsz; width = G; }
        else { g = fullw; r = j - jfull; width = nTn - fullw * G; }
        mt = x * mper + r / width;
        nt = g * G + r % width;
    } else {
        int swz = (nwg & 7) ? wg : ((wg & 7) * (nwg >> 3) + (wg >> 3));
        mt = swz / nTn; nt = swz - mt * nTn;
    }

    int t = threadIdx.x, wid = t >> 6, lane = t & 63;
    int wm = wid >> 2, wn = wid & 3;   // 2 x 4 wave grid; wave tile 128x64
    int lr = lane & 15, lq = lane >> 4;

    const unsigned short* Abase = A + (size_t)mt * GBM * K;
    const unsigned short* Bbase = Bw + (size_t)nt * GBN * K;

    // Staging: thread t covers rows r0, r0+64 at phys chunk pc; involution
    // swizzle logical chunk = pc ^ (row & 7) (64 === 0 mod 8: both rows share c0).
    int r0 = t >> 3;
    int pc = t & 7;
    int c0 = pc ^ (r0 & 7);
    const unsigned short* Aln = Abase + (size_t)r0 * K + c0 * 8;
    const unsigned short* Bln = Bbase + (size_t)r0 * K + c0 * 8;

    auto STAGE = [&](int slot, int mat, int half, int kb) {
        const unsigned short* g = (mat ? Bln : Aln) + (size_t)half * 128 * K + kb;
        unsigned short* d = &lds[slot * SLOT_SH + mat * TILE_SH + (half * 1024 + t) * 8];
        gload_lds16(g, d);
        gload_lds16(g + (size_t)64 * K, d + 512 * 8);
    };

    // Fragment ds_read offsets (shorts): phys chunk = (kk*4+lq) ^ (row&7),
    // row&7 == lr&7 for all fragment rows.
    int xo0 = lq ^ (lr & 7);
    int xo1 = (4 + lq) ^ (lr & 7);
    int offA[4][2], offB[2][2];
#pragma unroll
    for (int m = 0; m < 4; m++) {
        int row = wm * 128 + m * 16 + lr;
        offA[m][0] = (row * 8 + xo0) * 8;
        offA[m][1] = (row * 8 + xo1) * 8;
    }
#pragma unroll
    for (int n = 0; n < 2; n++) {
        int row = wn * 64 + n * 16 + lr;
        offB[n][0] = TILE_SH + (row * 8 + xo0) * 8;
        offB[n][1] = TILE_SH + (row * 8 + xo1) * 8;
    }

    f32x4 acc[8][4];
#pragma unroll
    for (int m = 0; m < 8; m++)
#pragma unroll
        for (int n = 0; n < 4; n++) acc[m][n] = (f32x4){0.f, 0.f, 0.f, 0.f};

    // Double register sets: arE (A quad mq=0), arO (mq=1), b0 (nq=0), b1 (nq=1).
    bf16x8 arE[8], arO[8], b0[4], b1[4];

    auto LD_A = [&](int slot, int mq, bf16x8* ar) {
        int base = slot * SLOT_SH + mq * 4096;
#pragma unroll
        for (int m = 0; m < 4; m++)
#pragma unroll
            for (int kk = 0; kk < 2; kk++)
                ar[m * 2 + kk] = *reinterpret_cast<const bf16x8*>(&lds[base + offA[m][kk]]);
    };
    auto LD_B = [&](int slot, int nq, bf16x8* b) {
        int base = slot * SLOT_SH + nq * 2048;
#pragma unroll
        for (int n = 0; n < 2; n++)
#pragma unroll
            for (int kk = 0; kk < 2; kk++)
                b[n * 2 + kk] = *reinterpret_cast<const bf16x8*>(&lds[base + offB[n][kk]]);
    };
    auto MMA = [&](int mq, int nq, bf16x8* ar, bf16x8* b) {
        __builtin_amdgcn_s_setprio(1);
#pragma unroll
        for (int m = 0; m < 4; m++)
#pragma unroll
            for (int n = 0; n < 2; n++)
#pragma unroll
                for (int kk = 0; kk < 2; kk++)
                    acc[mq * 4 + m][nq * 2 + n] = __builtin_amdgcn_mfma_f32_16x16x32_bf16(
                        ar[m * 2 + kk], b[n * 2 + kk], acc[mq * 4 + m][nq * 2 + n], 0, 0, 0);
        __builtin_amdgcn_s_setprio(0);
    };

    int NTm1 = K / GBK - 1;   // 63
    int NI = (K / GBK) / 2;   // 32

    // Prologue: slot0 full (8 loads), slot1.B (4 loads); preload ph1 regs.
    STAGE(0, 0, 0, 0);
    STAGE(0, 0, 1, 0);
    STAGE(0, 1, 0, 0);
    STAGE(0, 1, 1, 0);
    STAGE(1, 1, 0, GBK);
    STAGE(1, 1, 1, GBK);
    WAITV(4);   // slot0 resident; slot1.B (4) may fly
    BAR();
    LD_A(0, 0, arE);
    LD_B(0, 0, b0);

    for (int i = 0; i < NI; ++i) {
        int kb1 = min(2 * i + 1, NTm1) * GBK;  // slot1.A (real tile tau1)
        int kb2 = min(2 * i + 2, NTm1) * GBK;  // slot0 restage
        int kb3 = min(2 * i + 3, NTm1) * GBK;  // slot1.B restage

        // ph1: MMA slot0 Q(0,0); prefetch b1<-slot0.B1; stage s1A.h0
        WAITL0();
        LD_B(0, 1, b1);
        STAGE(1, 0, 0, kb1);
        SCHED0();
        MMA(0, 0, arE, b0);
        BAR();
        // ph2: Q(0,1); prefetch arO<-slot0.A1; stage s1A.h1
        WAITL0();
        LD_A(0, 1, arO);
        STAGE(1, 0, 1, kb1);
        SCHED0();
        MMA(0, 1, arE, b1);
        BAR();
        // ph3: Q(1,0); stage s0B.h0; vmcnt(2) forces slot1.A + prev slot1.B resident
        WAITL0();
        STAGE(0, 1, 0, kb2);
        SCHED0();
        MMA(1, 0, arO, b0);
        WAITV(2);
        BAR();
        // ph4: Q(1,1); prefetch arE<-slot1.A0, b0<-slot1.B0; stage s0B.h1
        WAITL0();
        LD_A(1, 0, arE);
        LD_B(1, 0, b0);
        STAGE(0, 1, 1, kb2);
        SCHED0();
        MMA(1, 1, arO, b1);
        BAR();
        // ph5: slot1 Q(0,0); prefetch b1<-slot1.B1; stage s0A.h0
        WAITL0();
        LD_B(1, 1, b1);
        STAGE(0, 0, 0, kb2);
        SCHED0();
        MMA(0, 0, arE, b0);
        BAR();
        // ph6: Q(0,1); prefetch arO<-slot1.A1; stage s0A.h1
        WAITL0();
        LD_A(1, 1, arO);
        STAGE(0, 0, 1, kb2);
        SCHED0();
        MMA(0, 1, arE, b1);
        BAR();
        // ph7: Q(1,0); stage s1B.h0; vmcnt(2) forces restaged slot0 resident
        WAITL0();
        STAGE(1, 1, 0, kb3);
        SCHED0();
        MMA(1, 0, arO, b0);
        WAITV(2);
        BAR();
        // ph8: Q(1,1); prefetch arE<-slot0.A0, b0<-slot0.B0 (next K-pair); stage s1B.h1
        WAITL0();
        LD_A(0, 0, arE);
        LD_B(0, 0, b0);
        STAGE(1, 1, 1, kb3);
        SCHED0();
        MMA(1, 1, arO, b1);
        BAR();
    }

    // Epilogue: bias + store. C/D layout: col = lane&15, row = (lane>>4)*4 + reg.
    float bvv[4];
#pragma unroll
    for (int n = 0; n < 4; n++) bvv[n] = bias[nt * GBN + wn * 64 + n * 16 + lr];

#pragma unroll
    for (int m = 0; m < 8; m++) {
#pragma unroll
        for (int r = 0; r < 4; r++) {
            size_t row = (size_t)(mt * GBM + wm * 128 + m * 16 + lq * 4 + r);
            float* Crow = C + row * N + nt * GBN + wn * 64 + lr;
#pragma unroll
            for (int n = 0; n < 4; n++) Crow[n * 16] = acc[m][n][r] + bvv[n];
        }
    }
}

extern "C" void kernel_launch(void* const* d_in, const int* in_sizes, int n_in,
                              void* d_out, int out_size, void* d_ws, size_t ws_size,
                              hipStream_t stream) {
    const float* x = (const float*)d_in[0];
    const float* w = (const float*)d_in[1];
    const float* bias = (const float*)d_in[2];
    float* y = (float*)d_out;

    int O = in_sizes[2];          // 11008
    int K = in_sizes[1] / O;      // 4096
    int T = in_sizes[0] / K;      // 8192 tokens

    unsigned short* xdq = (unsigned short*)d_ws;
    size_t xbytes = ((size_t)T * K * 2 + 255) & ~(size_t)255;
    unsigned short* wdq = (unsigned short*)((char*)d_ws + xbytes);

    long ngroups = (long)T * (K / 128);
    qd_x_kernel<<<dim3((unsigned)((ngroups + 3) / 4)), dim3(256), 0, stream>>>(x, xdq, ngroups);
    qd_w_kernel<<<dim3(K / 128, O / 128), dim3(256), 0, stream>>>(w, wdq, K);

    int grid = (T / GBM) * (O / GBN);
    gemm8p_kernel<<<dim3(grid), dim3(512), 0, stream>>>(xdq, wdq, bias, y, T, O, K);
}

// Round 6
// 703.348 us; speedup vs baseline: 1.6707x; 1.0382x over previous
//
#include <hip/hip_runtime.h>
#include <hip/hip_bf16.h>
#include <stdint.h>

#define QMAXF 127.0f

typedef __attribute__((ext_vector_type(4))) float f32x4;
typedef __attribute__((ext_vector_type(4))) int i32x4;

typedef __attribute__((address_space(1))) void gbl_void;
typedef __attribute__((address_space(3))) void lds_void;

__device__ __forceinline__ void gload_lds16(const void* g, void* l) {
    __builtin_amdgcn_global_load_lds((const gbl_void*)g, (lds_void*)l, 16, 0, 0);
}

// ---------------------------------------------------------------------------
// Kernel 1: per-token, per-128-col-group INT8 quant of activations.
// Outputs: q_x int8 [T,K]; scale transposed sxT[kb][T] (f32).
// ---------------------------------------------------------------------------
__global__ __launch_bounds__(256) void qd_x_kernel(const float* __restrict__ x,
                                                   char* __restrict__ qx,
                                                   float* __restrict__ sxT,
                                                   long ngroups, int nkb, int T) {
    long gw = ((long)blockIdx.x * blockDim.x + threadIdx.x) >> 6;
    int lane = threadIdx.x & 63;
    if (gw >= ngroups) return;

    float2 v = *(reinterpret_cast<const float2*>(x) + gw * 64 + lane);
    float a = fmaxf(fabsf(v.x), fabsf(v.y));
#pragma unroll
    for (int off = 32; off; off >>= 1) a = fmaxf(a, __shfl_xor(a, off));

    float scale = a > 0.f ? a / QMAXF : 1.f;
    int q0 = (int)fminf(fmaxf(rintf(v.x / scale), -QMAXF), QMAXF);
    int q1 = (int)fminf(fmaxf(rintf(v.y / scale), -QMAXF), QMAXF);
    unsigned short packed = (unsigned short)((q0 & 0xFF) | ((q1 & 0xFF) << 8));
    reinterpret_cast<unsigned short*>(qx)[gw * 64 + lane] = packed;

    if (lane == 0) {
        int t = (int)(gw / nkb), kb = (int)(gw - (long)t * nkb);
        sxT[(size_t)kb * T + t] = scale;
    }
}

// ---------------------------------------------------------------------------
// Kernel 2: 128x128 blockwise INT8 quant of weights.
// Outputs: q_w int8 [O,K]; scale_w [O/128][K/128].
// ---------------------------------------------------------------------------
__global__ __launch_bounds__(256) void qd_w_kernel(const float* __restrict__ w,
                                                   char* __restrict__ qw,
                                                   float* __restrict__ sw,
                                                   int K, int nkb) {
    int kb = blockIdx.x, ob = blockIdx.y;
    size_t base = (size_t)ob * 128 * K + (size_t)kb * 128;
    int t = threadIdx.x;

    float4 v[16];
    float a = 0.f;
#pragma unroll
    for (int i = 0; i < 16; i++) {
        int f = i * 256 + t;
        int row = f >> 5, c4 = f & 31;
        v[i] = *reinterpret_cast<const float4*>(w + base + (size_t)row * K + c4 * 4);
        a = fmaxf(a, fmaxf(fmaxf(fabsf(v[i].x), fabsf(v[i].y)),
                           fmaxf(fabsf(v[i].z), fabsf(v[i].w))));
    }
#pragma unroll
    for (int off = 32; off; off >>= 1) a = fmaxf(a, __shfl_xor(a, off));

    __shared__ float red[4];
    if ((t & 63) == 0) red[t >> 6] = a;
    __syncthreads();
    a = fmaxf(fmaxf(red[0], red[1]), fmaxf(red[2], red[3]));

    float scale = a > 0.f ? a / QMAXF : 1.f;
    if (t == 0) sw[(size_t)ob * nkb + kb] = scale;
#pragma unroll
    for (int i = 0; i < 16; i++) {
        int f = i * 256 + t;
        int row = f >> 5, c4 = f & 31;
        int q0 = (int)fminf(fmaxf(rintf(v[i].x / scale), -QMAXF), QMAXF);
        int q1 = (int)fminf(fmaxf(rintf(v[i].y / scale), -QMAXF), QMAXF);
        int q2 = (int)fminf(fmaxf(rintf(v[i].z / scale), -QMAXF), QMAXF);
        int q3 = (int)fminf(fmaxf(rintf(v[i].w / scale), -QMAXF), QMAXF);
        unsigned int p = (q0 & 0xFF) | ((q1 & 0xFF) << 8) | ((q2 & 0xFF) << 16) |
                         ((unsigned int)(q3 & 0xFF) << 24);
        *reinterpret_cast<unsigned int*>(qw + base + (size_t)row * K + c4 * 4) = p;
    }
}

// ---------------------------------------------------------------------------
// Kernel 3: exact INT8 GEMM. y[t,o] = sum_kb sx[t,kb]*sw[o/128,kb]*
//           (sum_{k in kb} qx*qw) + bias[o].
// 256x256 tile; iter = one 128-wide K-block = one quant group; 2 LDS slots
// (64 KB each: A 32K + B 32K int8); 4 phases/iter (quadrants Q00,Q01,Q11,Q10),
// each {ds_read frags + stage -> BAR -> lgkm0 -> 16 i8-MFMA (K=64, C-chained
// zero init) -> f32 fixup -> BAR}. Stages of next slot in ph1-2; WAITV(0) at
// iter end only (nothing younger in flight => counted semantics). XOR chunk
// swizzle identical to bf16 case (8 x 16B chunks/row). R5 XCD 2D window.
// ---------------------------------------------------------------------------
#define GBM 256
#define GBN 256
#define SLOT_BY 65536          // 64 KB: A tile 32 KB + B tile 32 KB (int8)

#define BAR()                              \
    do {                                   \
        asm volatile("" ::: "memory");     \
        __builtin_amdgcn_s_barrier();      \
        asm volatile("" ::: "memory");     \
    } while (0)
#define WAITL0()                                          \
    do {                                                  \
        asm volatile("s_waitcnt lgkmcnt(0)" ::: "memory");\
        __builtin_amdgcn_sched_barrier(0);                \
    } while (0)
#define WAITV0() asm volatile("s_waitcnt vmcnt(0)" ::: "memory")
#define SCHED0() __builtin_amdgcn_sched_barrier(0)

__global__ __launch_bounds__(512, 2) void gemm_i8_kernel(
    const char* __restrict__ Aq,    // [M,K] int8
    const char* __restrict__ Bq,    // [N,K] int8
    const float* __restrict__ sxT,  // [K/128][M]
    const float* __restrict__ swp,  // [N/128][K/128]
    const float* __restrict__ bias,
    float* __restrict__ C,          // [M,N] f32
    int M, int N, int K) {
    __shared__ alignas(16) unsigned char lds8[2 * SLOT_BY];  // 128 KiB

    int nTm = M / GBM, nTn = N / GBN;
    int nwg = gridDim.x, wg = blockIdx.x;
    int mt, nt;
    if ((nTm & 7) == 0 && (32 % (nTm >> 3)) == 0) {
        int x = wg & 7, j = wg >> 3;
        int mper = nTm >> 3;
        int G = 32 / mper;
        int wsz = mper * G;
        int fullw = nTn / G;
        int jfull = fullw * wsz;
        int g, r, width;
        if (j < jfull) { g = j / wsz; r = j - g * wsz; width = G; }
        else { g = fullw; r = j - jfull; width = nTn - fullw * G; }
        mt = x * mper + r / width;
        nt = g * G + r % width;
    } else {
        int swz = (nwg & 7) ? wg : ((wg & 7) * (nwg >> 3) + (wg >> 3));
        mt = swz / nTn; nt = swz - mt * nTn;
    }

    int t = threadIdx.x, wid = t >> 6, lane = t & 63;
    int wm = wid >> 2, wn = wid & 3;   // 2 x 4 wave grid; wave tile 128x64
    int lr = lane & 15, lq = lane >> 4;
    int nkb = K >> 7;                  // K/128

    const char* Abase = Aq + (size_t)mt * GBM * K;
    const char* Bbase = Bq + (size_t)nt * GBN * K;

    // Staging: half-tile = 128 rows x 128 B = 1024 chunks of 16 B; thread t
    // covers chunks t and 512+t. Involution swizzle: logical chunk =
    // phys ^ (row & 7).
    int cid0 = t, cid1 = 512 + t;
    int rl0 = cid0 >> 3, rl1 = cid1 >> 3;
    int pc0 = cid0 & 7, pc1 = cid1 & 7;
    int gc0 = (pc0 ^ (rl0 & 7)) * 16, gc1 = (pc1 ^ (rl1 & 7)) * 16;

    auto STAGE = [&](int slot, int mat, int half, int kb) {
        const char* gb = (mat ? Bbase : Abase) + (size_t)(half * 128) * K + kb;
        unsigned char* db = lds8 + slot * SLOT_BY + mat * 32768 + half * 16384;
        gload_lds16(gb + (size_t)rl0 * K + gc0, db + cid0 * 16);
        gload_lds16(gb + (size_t)rl1 * K + gc1, db + cid1 * 16);
    };

    // Fragment offsets (bytes within slot): row*128 + (chunk ^ (row&7))*16,
    // chunk = kk*4 + lq; row&7 == lr&7 for all fragment rows.
    int offA[4][2], offB[2][2];
#pragma unroll
    for (int m = 0; m < 4; m++) {
        int row = wm * 128 + m * 16 + lr;
#pragma unroll
        for (int kk = 0; kk < 2; kk++)
            offA[m][kk] = row * 128 + (((kk * 4 + lq) ^ (lr & 7)) << 4);
    }
#pragma unroll
    for (int n = 0; n < 2; n++) {
        int row = wn * 64 + n * 16 + lr;
#pragma unroll
        for (int kk = 0; kk < 2; kk++)
            offB[n][kk] = 32768 + row * 128 + (((kk * 4 + lq) ^ (lr & 7)) << 4);
    }

    f32x4 facc[8][4];
#pragma unroll
    for (int m = 0; m < 8; m++)
#pragma unroll
        for (int n = 0; n < 4; n++) facc[m][n] = (f32x4){0.f, 0.f, 0.f, 0.f};

    i32x4 a[4][2], b[2][2], ia[4][2];

    auto LDA = [&](int slot, int mq) {
        const unsigned char* base = lds8 + slot * SLOT_BY + mq * 8192;
#pragma unroll
        for (int m = 0; m < 4; m++)
#pragma unroll
            for (int kk = 0; kk < 2; kk++)
                a[m][kk] = *reinterpret_cast<const i32x4*>(base + offA[m][kk]);
    };
    auto LDB = [&](int slot, int nq) {
        const unsigned char* base = lds8 + slot * SLOT_BY + nq * 4096;
#pragma unroll
        for (int n = 0; n < 2; n++)
#pragma unroll
            for (int kk = 0; kk < 2; kk++)
                b[n][kk] = *reinterpret_cast<const i32x4*>(base + offB[n][kk]);
    };
    auto MMA = [&]() {
        __builtin_amdgcn_s_setprio(1);
#pragma unroll
        for (int m = 0; m < 4; m++)
#pragma unroll
            for (int n = 0; n < 2; n++) {
                ia[m][n] = __builtin_amdgcn_mfma_i32_16x16x64_i8(
                    a[m][0], b[n][0], (i32x4){0, 0, 0, 0}, 0, 0, 0);
                ia[m][n] = __builtin_amdgcn_mfma_i32_16x16x64_i8(
                    a[m][1], b[n][1], ia[m][n], 0, 0, 0);
            }
        __builtin_amdgcn_s_setprio(0);
    };
    // Fixup: facc[mq*4+m][nq*2+n] += cvt(ia) * sx4[m] * sw
    f32x4 sx4[4];
    float sw;
    auto FIX = [&](int mq, int nq) {
#pragma unroll
        for (int m = 0; m < 4; m++) {
            f32x4 sxw = sx4[m] * sw;
#pragma unroll
            for (int n = 0; n < 2; n++) {
                f32x4 cv;
#pragma unroll
                for (int r = 0; r < 4; r++) cv[r] = (float)ia[m][n][r];
                facc[mq * 4 + m][nq * 2 + n] += cv * sxw;
            }
        }
    };
    int sxrow0 = mt * GBM + wm * 128 + lq * 4;   // + mq*64 + m*16
    auto LDSX = [&](int i, int mq) {
#pragma unroll
        for (int m = 0; m < 4; m++)
            sx4[m] = *reinterpret_cast<const f32x4*>(
                sxT + (size_t)i * M + sxrow0 + mq * 64 + m * 16);
    };

    int swbase = (nt * 2 + (wn >> 1)) * nkb;

    // Prologue: slot0 <- K-block 0.
    STAGE(0, 0, 0, 0); STAGE(0, 0, 1, 0);
    STAGE(0, 1, 0, 0); STAGE(0, 1, 1, 0);
    WAITV0();
    BAR();

    for (int i = 0; i < nkb; ++i) {
        int p = i & 1, q = p ^ 1;
        int knext = (i + 1 < nkb ? i + 1 : i) * 128;

        // ph1: Q(0,0); stage next A.h0+B.h0; load sx(mq0), sw
        LDA(p, 0); LDB(p, 0);
        STAGE(q, 0, 0, knext); STAGE(q, 1, 0, knext);
        LDSX(i, 0);
        sw = swp[swbase + i];
        BAR(); WAITL0();
        MMA(); FIX(0, 0);
        BAR();
        // ph2: Q(0,1); stage next A.h1+B.h1
        LDB(p, 1);
        STAGE(q, 0, 1, knext); STAGE(q, 1, 1, knext);
        BAR(); WAITL0();
        MMA(); FIX(0, 1);
        BAR();
        // ph3: Q(1,1); load sx(mq1)
        LDA(p, 1);
        LDSX(i, 1);
        BAR(); WAITL0();
        MMA(); FIX(1, 1);
        BAR();
        // ph4: Q(1,0); drain stages (nothing younger in flight) at iter end
        LDB(p, 0);
        BAR(); WAITL0();
        MMA(); FIX(1, 0);
        WAITV0();
        BAR();
    }

    // Epilogue: bias + store. C/D layout: col = lane&15, row = (lane>>4)*4 + reg.
    float bvv[4];
#pragma unroll
    for (int n = 0; n < 4; n++) bvv[n] = bias[nt * GBN + wn * 64 + n * 16 + lr];

#pragma unroll
    for (int m = 0; m < 8; m++) {
#pragma unroll
        for (int r = 0; r < 4; r++) {
            size_t row = (size_t)(mt * GBM + wm * 128 + m * 16 + lq * 4 + r);
            float* Crow = C + row * N + nt * GBN + wn * 64 + lr;
#pragma unroll
            for (int n = 0; n < 4; n++) Crow[n * 16] = facc[m][n][r] + bvv[n];
        }
    }
}

extern "C" void kernel_launch(void* const* d_in, const int* in_sizes, int n_in,
                              void* d_out, int out_size, void* d_ws, size_t ws_size,
                              hipStream_t stream) {
    const float* x = (const float*)d_in[0];
    const float* w = (const float*)d_in[1];
    const float* bias = (const float*)d_in[2];
    float* y = (float*)d_out;

    int O = in_sizes[2];          // 11008
    int K = in_sizes[1] / O;      // 4096
    int T = in_sizes[0] / K;      // 8192 tokens
    int nkb = K / 128;            // 32

    char* qx = (char*)d_ws;
    size_t off = ((size_t)T * K + 255) & ~(size_t)255;
    char* qw = (char*)d_ws + off;
    off += ((size_t)O * K + 255) & ~(size_t)255;
    float* sxT = (float*)((char*)d_ws + off);
    off += ((size_t)nkb * T * 4 + 255) & ~(size_t)255;
    float* sw = (float*)((char*)d_ws + off);

    long ngroups = (long)T * nkb;
    qd_x_kernel<<<dim3((unsigned)((ngroups + 3) / 4)), dim3(256), 0, stream>>>(
        x, qx, sxT, ngroups, nkb, T);
    qd_w_kernel<<<dim3(nkb, O / 128), dim3(256), 0, stream>>>(w, qw, sw, K, nkb);

    int grid = (T / GBM) * (O / GBN);
    gemm_i8_kernel<<<dim3(grid), dim3(512), 0, stream>>>(qx, qw, sxT, sw, bias, y,
                                                         T, O, K);
}